// Round 21
// baseline (50.709 us; speedup 1.0000x reference)
//
#include <hip/hip_runtime.h>
#include <math.h>

#define NN 8192
#define CC 256
#define OO 64
#define JW 8      // j's per wave in k_rank

using short8 = __attribute__((ext_vector_type(8))) short;
using f32x4  = __attribute__((ext_vector_type(4))) float;

// split one fp32 -> bf16 hi (truncate) + bf16 lo (exact remainder, truncated)
__device__ __forceinline__ void split2(const float a, const float b,
                                       unsigned& hp, unsigned& lp) {
  const unsigned ua = __float_as_uint(a), ub = __float_as_uint(b);
  hp = (ua >> 16) | (ub & 0xffff0000u);
  const float la = a - __uint_as_float(ua & 0xffff0000u);
  const float lb = b - __uint_as_float(ub & 0xffff0000u);
  lp = (__float_as_uint(la) >> 16) | (__float_as_uint(lb) & 0xffff0000u);
}

union PackB { unsigned u[4]; short8 s; };

// ============ K1: MFMA split-bf16 GEMM (16 rows x 64 cols per block, grid 512) ============
__global__ __launch_bounds__(256) void k_gemm(
    const float* __restrict__ x, const float* __restrict__ W1,
    const float* __restrict__ b1, const float* __restrict__ a1,
    const float* __restrict__ ba1, const float* __restrict__ a2,
    const float* __restrict__ ba2,
    float* __restrict__ seq,
    float* __restrict__ f1, float* __restrict__ f2,
    float* __restrict__ E1, float* __restrict__ E1s,
    float* __restrict__ eF2, float* __restrict__ eF2s,
    unsigned long long* __restrict__ keys /* [2][NN] */)
{
  __shared__ unsigned short xh[16][264];   // bf16 hi of x tile (pad 264 -> 2-way banks)
  __shared__ unsigned short xl[16][264];   // bf16 lo
  __shared__ float seq_l[16][66];
  const int t = threadIdx.x;
  const int lane = t & 63, wv = t >> 6;    // 4 waves
  const int r0 = blockIdx.x * 16;
  // ---- stage x rows r0..r0+15 as bf16 hi/lo ----
  for (int q = t; q < 1024; q += 256) {    // 1024 float4 = 16 rows x 256 c
    const int row = q >> 6, c4 = (q & 63) * 4;
    const float4 v = *(const float4*)(x + (size_t)(r0 + row)*CC + c4);
    unsigned hp0, lp0, hp1, lp1;
    split2(v.x, v.y, hp0, lp0);
    split2(v.z, v.w, hp1, lp1);
    const int di = (row*264 + c4) >> 1;    // dword index (c4 even)
    ((unsigned*)xh)[di]   = hp0; ((unsigned*)xh)[di+1] = hp1;
    ((unsigned*)xl)[di]   = lp0; ((unsigned*)xl)[di+1] = lp1;
  }
  __syncthreads();
  // ---- MFMA k-loop: wave wv -> cols 16wv..16wv+15 ----
  const int lr = lane & 15;                // A row / B col within tile
  const int ls = lane >> 4;                // k-slice 0..3
  const int o0 = wv * 16;
  const float* wrow = W1 + (size_t)(o0 + lr)*CC;
  const unsigned short* xhr = &xh[lr][0];
  const unsigned short* xlr = &xl[lr][0];
  f32x4 acc = {0.f, 0.f, 0.f, 0.f};
#pragma unroll
  for (int kc = 0; kc < CC; kc += 32) {
    const int ko = kc + ls*8;
    const short8 a_hi = *(const short8*)(xhr + ko);
    const short8 a_lo = *(const short8*)(xlr + ko);
    const float4 w0 = *(const float4*)(wrow + ko);
    const float4 w1 = *(const float4*)(wrow + ko + 4);
    PackB ph, pl;                          // packed dwords ARE the short8 bit-image
    split2(w0.x, w0.y, ph.u[0], pl.u[0]);
    split2(w0.z, w0.w, ph.u[1], pl.u[1]);
    split2(w1.x, w1.y, ph.u[2], pl.u[2]);
    split2(w1.z, w1.w, ph.u[3], pl.u[3]);
    acc = __builtin_amdgcn_mfma_f32_16x16x32_bf16(a_hi, ph.s, acc, 0, 0, 0);
    acc = __builtin_amdgcn_mfma_f32_16x16x32_bf16(a_lo, ph.s, acc, 0, 0, 0);
    acc = __builtin_amdgcn_mfma_f32_16x16x32_bf16(a_hi, pl.s, acc, 0, 0, 0);
  }
  // ---- store: C/D layout col=lane&15, row=(lane>>4)*4+j (HW-verified) ----
  const int col_g = o0 + lr;
  const float bb = b1[col_g];
#pragma unroll
  for (int j = 0; j < 4; ++j) {
    const int rowt = 4*ls + j;
    const float val = acc[j] + bb;
    seq[(size_t)(r0 + rowt)*OO + col_g] = val;
    seq_l[rowt][col_g] = val;
  }
  __syncthreads();
  // ---- f1/f2 + exp tables + keys: wave wv handles rows 4wv..4wv+3 ----
  const float A1 = a1[lane], A2 = a2[lane];
#pragma unroll
  for (int rr = 0; rr < 4; ++rr) {
    const int row = 4*wv + rr;
    const float v = seq_l[row][lane];
    float p1 = v*A1, p2 = v*A2;
#pragma unroll
    for (int d = 1; d < 64; d <<= 1) {
      p1 += __shfl_xor(p1, d, 64);
      p2 += __shfl_xor(p2, d, 64);
    }
    if (lane == 0) {
      const int i = r0 + row;
      const float t1 = p1 + ba1[0], t2 = p2 + ba2[0];
      f1[i] = t1; E1[i] = expf(t1); E1s[i] = expf(0.01f*t1);
      f2[i] = t2; eF2[i] = expf(t2); eF2s[i] = expf(0.01f*t2);
      unsigned u;
      u = __float_as_uint(t1); u = (u & 0x80000000u) ? ~u : (u | 0x80000000u);
      keys[i] = ((unsigned long long)u << 32) | (unsigned)i;
      u = __float_as_uint(t2); u = (u & 0x80000000u) ? ~u : (u | 0x80000000u);
      keys[NN + i] = ((unsigned long long)u << 32) | (unsigned)i;
    }
  }
}

// ============ K2: rank counting — ballot/popcount (scalar-pipe accumulate) ============
// 512 thr, grid 256, JW=8, b128 LDS reads
__global__ __launch_bounds__(512) void k_rank(
    const unsigned long long* __restrict__ keys,
    const float* __restrict__ f1, const float* __restrict__ E1,
    const float* __restrict__ E1s, const float* __restrict__ f2,
    const float* __restrict__ eF2, const float* __restrict__ eF2s,
    float* __restrict__ s1, float* __restrict__ se1, float* __restrict__ se1s,
    int* __restrict__ inv1,
    float* __restrict__ f2s, float* __restrict__ eF2srt,
    float* __restrict__ eF2ssrt, int* __restrict__ inv)
{
  __shared__ unsigned long long skl[NN];   // 64 KB
  const int t = threadIdx.x;
  const int lane = t & 63, wv = t >> 6;    // 8 waves
  const int b = blockIdx.x;
  const int arr = b >> 7;                  // 0: f1 keys (b<128), 1: f2 keys
  const int jbw = (b & 127)*64 + wv*JW;
  const unsigned long long* kb = keys + ((size_t)arr << 13);
  for (int q = t; q < NN/2; q += 512)
    ((ulonglong2*)skl)[q] = ((const ulonglong2*)kb)[q];
  __syncthreads();
  unsigned long long K[JW];
#pragma unroll
  for (int q = 0; q < JW; ++q) {
    const unsigned long long kk = skl[jbw + q];
    const unsigned lo = __builtin_amdgcn_readfirstlane((unsigned)kk);
    const unsigned hi = __builtin_amdgcn_readfirstlane((unsigned)(kk >> 32));
    K[q] = ((unsigned long long)hi << 32) | lo;
  }
  int cnt[JW];
#pragma unroll
  for (int q = 0; q < JW; ++q) cnt[q] = 0;
  const ulonglong2* s2 = (const ulonglong2*)skl;
#pragma unroll 4
  for (int c = 0; c < NN/128; ++c) {
    const ulonglong2 sk = s2[c*64 + lane];
#pragma unroll
    for (int q = 0; q < JW; ++q) {
      cnt[q] += __popcll(__ballot(sk.x < K[q]));   // v_cmp -> s_bcnt1 -> s_add
      cnt[q] += __popcll(__ballot(sk.y < K[q]));
    }
  }
#pragma unroll
  for (int q = 0; q < JW; ++q) {
    const int r = cnt[q];                  // wave-uniform, no reduction needed
    if (lane == 0) {
      const int i = jbw + q;
      if (arr == 0) {
        s1[r] = f1[i]; se1[r] = E1[i]; se1s[r] = E1s[i]; inv1[r] = i;
      } else {
        inv[r] = i; f2s[r] = f2[i]; eF2srt[r] = eF2[i]; eF2ssrt[r] = eF2s[i];
      }
    }
  }
}

// ============ K3: D-factors + kpos (LDS bsearch) + TU/TV chunk totals ============
__global__ __launch_bounds__(1024) void k_DT(
    const float* __restrict__ se1, const float* __restrict__ se1s,
    const float* __restrict__ s1g,
    const float* __restrict__ f2s, const float* __restrict__ eF2srt,
    const float* __restrict__ eF2ssrt, const int* __restrict__ inv,
    const float* __restrict__ seq,
    float* __restrict__ Bs, float* __restrict__ Es,
    int* __restrict__ kpos, float* __restrict__ TU, float* __restrict__ TV)
{
  __shared__ float s1l[NN];
  __shared__ float f2sl[NN];
  __shared__ float csA[256], csB[256];
  __shared__ float csEA[257], csEB[257];
  __shared__ float wsA[4], wsB[4];
  __shared__ float bsl[32], esl[32];
  __shared__ float redU[16][64], redV[16][64];
  const int t = threadIdx.x;
  const int b = blockIdx.x;
  const int wv = t >> 6, lane = t & 63;
  const float4 a0 = ((const float4*)se1 )[t*2];
  const float4 a1v = ((const float4*)se1 )[t*2+1];
  const float4 b0 = ((const float4*)se1s)[t*2];
  const float4 b1v = ((const float4*)se1s)[t*2+1];
  ((float4*)s1l)[t*2]   = ((const float4*)s1g)[t*2];
  ((float4*)s1l)[t*2+1] = ((const float4*)s1g)[t*2+1];
  ((float4*)f2sl)[t*2]   = ((const float4*)f2s)[t*2];
  ((float4*)f2sl)[t*2+1] = ((const float4*)f2s)[t*2+1];
  float sa = ((a0.x+a0.y)+(a0.z+a0.w)) + ((a1v.x+a1v.y)+(a1v.z+a1v.w));
  float sb = ((b0.x+b0.y)+(b0.z+b0.w)) + ((b1v.x+b1v.y)+(b1v.z+b1v.w));
  sa += __shfl_xor(sa, 1, 64); sb += __shfl_xor(sb, 1, 64);
  sa += __shfl_xor(sa, 2, 64); sb += __shfl_xor(sb, 2, 64);
  if ((t & 3) == 0) { csA[t>>2] = sa; csB[t>>2] = sb; }
  __syncthreads();
  if (t < 256) {
    float a = csA[t], bv = csB[t];
#pragma unroll
    for (int d = 1; d < 64; d <<= 1) {
      const float ua = __shfl_up(a, d, 64);
      const float ub = __shfl_up(bv, d, 64);
      if (lane >= d) { a += ua; bv += ub; }
    }
    csA[t] = a; csB[t] = bv;
    if (lane == 63) { wsA[wv] = a; wsB[wv] = bv; }
  }
  __syncthreads();
  if (t < 256) {
    float baseA = 0.f, baseB = 0.f;
    for (int q = 0; q < wv; ++q) { baseA += wsA[q]; baseB += wsB[q]; }
    csEA[t+1] = csA[t] + baseA;
    csEB[t+1] = csB[t] + baseB;
    if (t == 0) { csEA[0] = 0.f; csEB[0] = 0.f; }
  }
  __syncthreads();
  const int half = lane >> 5, m = lane & 31;
  {
    const int kk = b*32 + 2*wv + half;
    const float tgt = -f2sl[kk];
    int pos = 0;
#pragma unroll
    for (int s = NN; s; s >>= 1) {
      const int c = pos + s;
      if (c <= NN && s1l[c-1] < tgt) pos = c;
    }
    const int base = pos & ~31, cn = pos & 31;
    float ta = 0.f, tb = 0.f;
    if (m < cn) { ta = se1[base+m]; tb = se1s[base+m]; }
#pragma unroll
    for (int d = 1; d < 32; d <<= 1) {
      ta += __shfl_xor(ta, d, 64);
      tb += __shfl_xor(tb, d, 64);
    }
    if (m == 0) {
      const float PreA = csEA[pos>>5] + ta;
      const float PreB = csEB[pos>>5] + tb;
      const float T1 = csEA[256];
      const float e2 = eF2srt[kk], e2s = eF2ssrt[kk];
      const float D = fmaf(T1 - PreA, e2, PreB * e2s);
      const float bsv = e2 / D, esv = e2s / D;
      Bs[kk] = bsv; Es[kk] = esv;
      bsl[2*wv + half] = bsv; esl[2*wv + half] = esv;
    }
  }
  if (t < 32) {
    const int r = b*32 + t;
    const float tgt = -s1l[r];
    int pos = 0;
#pragma unroll
    for (int s = NN; s; s >>= 1) {
      const int c = pos + s;
      if (c <= NN && f2sl[c-1] < tgt) pos = c;
    }
    kpos[r] = pos;
  }
  __syncthreads();
  {
    const int kk0 = b*32 + 2*wv, kk1 = kk0 + 1;
    const float s0v = seq[(size_t)inv[kk0]*OO + lane];
    const float s1v = seq[(size_t)inv[kk1]*OO + lane];
    redU[wv][lane] = bsl[2*wv]*s0v + bsl[2*wv+1]*s1v;
    redV[wv][lane] = esl[2*wv]*s0v + esl[2*wv+1]*s1v;
  }
  __syncthreads();
  if (wv == 0) {
    float r = 0.f;
#pragma unroll
    for (int q = 0; q < 16; ++q) r += redU[q][lane];
    TU[b*64 + lane] = r;
  } else if (wv == 1) {
    float r = 0.f;
#pragma unroll
    for (int q = 0; q < 16; ++q) r += redV[q][lane];
    TV[b*64 + lane] = r;
  }
}

// ============ K4: merged prefix + output (no PU/PV tables), 1024 threads ============
__global__ __launch_bounds__(1024) void k_merge(
    const int* __restrict__ kpos, const int* __restrict__ inv,
    const int* __restrict__ inv1,
    const float* __restrict__ se1, const float* __restrict__ se1s,
    const float* __restrict__ Bs, const float* __restrict__ Es,
    const float* __restrict__ seq,
    const float* __restrict__ TU, const float* __restrict__ TV,
    float* __restrict__ out)
{
  __shared__ int kposl[NN];
  __shared__ float pu[33][64], pv[33][64];
  __shared__ float rA[16][64], rB[16][64], rC[16][64];
  __shared__ int bnd[2];
  const int t = threadIdx.x, lane = t & 63, wv = t >> 6, b = blockIdx.x;
  for (int q = t; q < NN/4; q += 1024)
    ((int4*)kposl)[q] = ((const int4*)kpos)[q];
  float pbu = 0.f, pbv = 0.f, ptu = 0.f;
  for (int c = wv; c < 256; c += 16) {
    const float tu = TU[c*64 + lane], tv = TV[c*64 + lane];
    ptu += tu;
    if (c < b) { pbu += tu; pbv += tv; }
  }
  rA[wv][lane] = pbu; rB[wv][lane] = pbv; rC[wv][lane] = ptu;
  {
    const int kk0 = b*32 + 2*wv, kk1 = kk0 + 1;
    const float sv0 = seq[(size_t)inv[kk0]*OO + lane];
    const float sv1 = seq[(size_t)inv[kk1]*OO + lane];
    pu[2*wv+1][lane] = Bs[kk0]*sv0; pv[2*wv+1][lane] = Es[kk0]*sv0;
    pu[2*wv+2][lane] = Bs[kk1]*sv1; pv[2*wv+2][lane] = Es[kk1]*sv1;
  }
  if (wv == 0) { pu[0][lane] = 0.f; pv[0][lane] = 0.f; }
  __syncthreads();
  if (t == 0) {
    const int hi = 32*b + 32 + (b == 255 ? 1 : 0);
    int pos = 0;
    for (int s = NN; s; s >>= 1) { const int c = pos+s; if (c <= NN && kposl[c-1] >= hi) pos = c; }
    bnd[0] = pos;
    pos = 0;
    const int lo = 32*b;
    for (int s = NN; s; s >>= 1) { const int c = pos+s; if (c <= NN && kposl[c-1] >= lo) pos = c; }
    bnd[1] = pos;
  }
  float base_u = 0.f, base_v = 0.f, utot = 0.f;
#pragma unroll
  for (int q = 0; q < 16; ++q) {
    base_u += rA[q][lane]; base_v += rB[q][lane]; utot += rC[q][lane];
  }
  for (int d = 1; d < 32; d <<= 1) {
    const int rowA = wv + 1;
    const int rowB = wv + 17;
    const int srcA = rowA - d, srcB = rowB - d;
    const float aA = (srcA >= 0) ? pu[srcA][lane] : 0.f;
    const float vA = (srcA >= 0) ? pv[srcA][lane] : 0.f;
    const float aB = (srcB >= 0) ? pu[srcB][lane] : 0.f;
    const float vB = (srcB >= 0) ? pv[srcB][lane] : 0.f;
    __syncthreads();
    pu[rowA][lane] += aA; pv[rowA][lane] += vA;
    pu[rowB][lane] += aB; pv[rowB][lane] += vB;
    __syncthreads();
  }
  const int r0 = bnd[0], r1 = bnd[1];
  for (int r = r0 + wv; r < r1; r += 16) {
    const int kl = kposl[r] - 32*b;
    const float ret = se1[r]*(utot - (base_u + pu[kl][lane]))
                    + se1s[r]*(base_v + pv[kl][lane]);
    out[(size_t)inv1[r]*OO + lane] = (ret > 0.f) ? ret : expm1f(ret);
  }
}

extern "C" void kernel_launch(void* const* d_in, const int* in_sizes, int n_in,
                              void* d_out, int out_size, void* d_ws, size_t ws_size,
                              hipStream_t stream)
{
  (void)in_sizes; (void)n_in; (void)out_size; (void)ws_size;
  const float* x   = (const float*)d_in[0];
  const float* W1  = (const float*)d_in[1];
  const float* b1  = (const float*)d_in[2];
  const float* a1  = (const float*)d_in[3];
  const float* ba1 = (const float*)d_in[4];
  const float* a2  = (const float*)d_in[5];
  const float* ba2 = (const float*)d_in[6];
  float* out = (float*)d_out;

  float* w = (float*)d_ws;
  size_t off = 0;
  auto alloc = [&](size_t n) { float* p = w + off; off += (n + 63) & ~(size_t)63; return p; };
  float* seq  = alloc((size_t)NN*OO);
  float* f1   = alloc(NN);
  float* f2   = alloc(NN);
  float* E1   = alloc(NN);
  float* E1s  = alloc(NN);
  float* eF2  = alloc(NN);
  float* eF2s = alloc(NN);
  unsigned long long* keys = (unsigned long long*)alloc((size_t)4*NN);
  int*   inv1 = (int*)alloc(NN);
  int*   inv  = (int*)alloc(NN);
  float* s1   = alloc(NN);
  float* se1  = alloc(NN);
  float* se1s = alloc(NN);
  float* f2s  = alloc(NN);
  float* eF2srt  = alloc(NN);
  float* eF2ssrt = alloc(NN);
  float* Bs   = alloc(NN);
  float* Es   = alloc(NN);
  int*   kpos = (int*)alloc(NN);
  float* TU   = alloc(256*64);
  float* TV   = alloc(256*64);

  k_gemm<<<512, 256, 0, stream>>>(x, W1, b1, a1, ba1, a2, ba2,
                                  seq, f1, f2, E1, E1s, eF2, eF2s, keys);
  k_rank<<<256, 512, 0, stream>>>(keys, f1, E1, E1s, f2, eF2, eF2s,
                                  s1, se1, se1s, inv1, f2s, eF2srt, eF2ssrt, inv);
  k_DT<<<256, 1024, 0, stream>>>(se1, se1s, s1, f2s, eF2srt, eF2ssrt,
                                 inv, seq, Bs, Es, kpos, TU, TV);
  k_merge<<<256, 1024, 0, stream>>>(kpos, inv, inv1, se1, se1s, Bs, Es,
                                    seq, TU, TV, out);
}

// Round 22
// 46.785 us; speedup vs baseline: 1.0839x; 1.0839x over previous
//
#include <hip/hip_runtime.h>
#include <math.h>

#define NN 8192
#define CC 256
#define OO 64
#define JW 8      // j's per wave in k_rank

using short8 = __attribute__((ext_vector_type(8))) short;
using f32x4  = __attribute__((ext_vector_type(4))) float;

// split one fp32 -> bf16 hi (truncate) + bf16 lo (exact remainder, truncated)
__device__ __forceinline__ void split2(const float a, const float b,
                                       unsigned& hp, unsigned& lp) {
  const unsigned ua = __float_as_uint(a), ub = __float_as_uint(b);
  hp = (ua >> 16) | (ub & 0xffff0000u);
  const float la = a - __uint_as_float(ua & 0xffff0000u);
  const float lb = b - __uint_as_float(ub & 0xffff0000u);
  lp = (__float_as_uint(la) >> 16) | (__float_as_uint(lb) & 0xffff0000u);
}

union PackB { unsigned u[4]; short8 s; };

// ============ K1: MFMA split-bf16 GEMM (16 rows x 64 cols per block, grid 512) ============
__global__ __launch_bounds__(256) void k_gemm(
    const float* __restrict__ x, const float* __restrict__ W1,
    const float* __restrict__ b1, const float* __restrict__ a1,
    const float* __restrict__ ba1, const float* __restrict__ a2,
    const float* __restrict__ ba2,
    float* __restrict__ seq,
    float* __restrict__ f1, float* __restrict__ f2,
    float* __restrict__ E1, float* __restrict__ E1s,
    float* __restrict__ eF2, float* __restrict__ eF2s,
    unsigned long long* __restrict__ keys /* [2][NN] */)
{
  __shared__ unsigned short xh[16][264];   // bf16 hi of x tile (pad 264 -> 2-way banks)
  __shared__ unsigned short xl[16][264];   // bf16 lo
  __shared__ float seq_l[16][66];
  const int t = threadIdx.x;
  const int lane = t & 63, wv = t >> 6;    // 4 waves
  const int r0 = blockIdx.x * 16;
  // ---- stage x rows r0..r0+15 as bf16 hi/lo ----
  for (int q = t; q < 1024; q += 256) {    // 1024 float4 = 16 rows x 256 c
    const int row = q >> 6, c4 = (q & 63) * 4;
    const float4 v = *(const float4*)(x + (size_t)(r0 + row)*CC + c4);
    unsigned hp0, lp0, hp1, lp1;
    split2(v.x, v.y, hp0, lp0);
    split2(v.z, v.w, hp1, lp1);
    const int di = (row*264 + c4) >> 1;    // dword index (c4 even)
    ((unsigned*)xh)[di]   = hp0; ((unsigned*)xh)[di+1] = hp1;
    ((unsigned*)xl)[di]   = lp0; ((unsigned*)xl)[di+1] = lp1;
  }
  __syncthreads();
  // ---- MFMA k-loop: wave wv -> cols 16wv..16wv+15 ----
  const int lr = lane & 15;                // A row / B col within tile
  const int ls = lane >> 4;                // k-slice 0..3
  const int o0 = wv * 16;
  const float* wrow = W1 + (size_t)(o0 + lr)*CC;
  const unsigned short* xhr = &xh[lr][0];
  const unsigned short* xlr = &xl[lr][0];
  f32x4 acc = {0.f, 0.f, 0.f, 0.f};
#pragma unroll
  for (int kc = 0; kc < CC; kc += 32) {
    const int ko = kc + ls*8;
    const short8 a_hi = *(const short8*)(xhr + ko);
    const short8 a_lo = *(const short8*)(xlr + ko);
    const float4 w0 = *(const float4*)(wrow + ko);
    const float4 w1 = *(const float4*)(wrow + ko + 4);
    PackB ph, pl;                          // packed dwords ARE the short8 bit-image
    split2(w0.x, w0.y, ph.u[0], pl.u[0]);
    split2(w0.z, w0.w, ph.u[1], pl.u[1]);
    split2(w1.x, w1.y, ph.u[2], pl.u[2]);
    split2(w1.z, w1.w, ph.u[3], pl.u[3]);
    acc = __builtin_amdgcn_mfma_f32_16x16x32_bf16(a_hi, ph.s, acc, 0, 0, 0);
    acc = __builtin_amdgcn_mfma_f32_16x16x32_bf16(a_lo, ph.s, acc, 0, 0, 0);
    acc = __builtin_amdgcn_mfma_f32_16x16x32_bf16(a_hi, pl.s, acc, 0, 0, 0);
  }
  // ---- store: C/D layout col=lane&15, row=(lane>>4)*4+j (HW-verified) ----
  const int col_g = o0 + lr;
  const float bb = b1[col_g];
#pragma unroll
  for (int j = 0; j < 4; ++j) {
    const int rowt = 4*ls + j;
    const float val = acc[j] + bb;
    seq[(size_t)(r0 + rowt)*OO + col_g] = val;
    seq_l[rowt][col_g] = val;
  }
  __syncthreads();
  // ---- f1/f2 + exp tables + keys: wave wv handles rows 4wv..4wv+3 ----
  const float A1 = a1[lane], A2 = a2[lane];
#pragma unroll
  for (int rr = 0; rr < 4; ++rr) {
    const int row = 4*wv + rr;
    const float v = seq_l[row][lane];
    float p1 = v*A1, p2 = v*A2;
#pragma unroll
    for (int d = 1; d < 64; d <<= 1) {
      p1 += __shfl_xor(p1, d, 64);
      p2 += __shfl_xor(p2, d, 64);
    }
    if (lane == 0) {
      const int i = r0 + row;
      const float t1 = p1 + ba1[0], t2 = p2 + ba2[0];
      f1[i] = t1; E1[i] = expf(t1); E1s[i] = expf(0.01f*t1);
      f2[i] = t2; eF2[i] = expf(t2); eF2s[i] = expf(0.01f*t2);
      unsigned u;
      u = __float_as_uint(t1); u = (u & 0x80000000u) ? ~u : (u | 0x80000000u);
      keys[i] = ((unsigned long long)u << 32) | (unsigned)i;
      u = __float_as_uint(t2); u = (u & 0x80000000u) ? ~u : (u | 0x80000000u);
      keys[NN + i] = ((unsigned long long)u << 32) | (unsigned)i;
    }
  }
}

// ============ K2: rank counting (512 thr, grid 256, JW=8, b128 LDS reads, unroll 4) ============
__global__ __launch_bounds__(512) void k_rank(
    const unsigned long long* __restrict__ keys,
    const float* __restrict__ f1, const float* __restrict__ E1,
    const float* __restrict__ E1s, const float* __restrict__ f2,
    const float* __restrict__ eF2, const float* __restrict__ eF2s,
    float* __restrict__ s1, float* __restrict__ se1, float* __restrict__ se1s,
    int* __restrict__ inv1,
    float* __restrict__ f2s, float* __restrict__ eF2srt,
    float* __restrict__ eF2ssrt, int* __restrict__ inv)
{
  __shared__ unsigned long long skl[NN];   // 64 KB
  const int t = threadIdx.x;
  const int lane = t & 63, wv = t >> 6;    // 8 waves
  const int b = blockIdx.x;
  const int arr = b >> 7;                  // 0: f1 keys (b<128), 1: f2 keys
  const int jbw = (b & 127)*64 + wv*JW;
  const unsigned long long* kb = keys + ((size_t)arr << 13);
  for (int q = t; q < NN/2; q += 512)
    ((ulonglong2*)skl)[q] = ((const ulonglong2*)kb)[q];
  __syncthreads();
  unsigned long long K[JW];
#pragma unroll
  for (int q = 0; q < JW; ++q) {
    const unsigned long long kk = skl[jbw + q];
    const unsigned lo = __builtin_amdgcn_readfirstlane((unsigned)kk);
    const unsigned hi = __builtin_amdgcn_readfirstlane((unsigned)(kk >> 32));
    K[q] = ((unsigned long long)hi << 32) | lo;
  }
  int cnt[JW];
#pragma unroll
  for (int q = 0; q < JW; ++q) cnt[q] = 0;
  const ulonglong2* s2 = (const ulonglong2*)skl;
#pragma unroll 4
  for (int c = 0; c < NN/128; ++c) {
    const ulonglong2 sk = s2[c*64 + lane];
#pragma unroll
    for (int q = 0; q < JW; ++q) {
      cnt[q] += (sk.x < K[q]) ? 1 : 0;
      cnt[q] += (sk.y < K[q]) ? 1 : 0;
    }
  }
#pragma unroll
  for (int q = 0; q < JW; ++q) {
    int r = cnt[q];
#pragma unroll
    for (int d = 1; d < 64; d <<= 1) r += __shfl_xor(r, d, 64);
    if (lane == 0) {
      const int i = jbw + q;
      if (arr == 0) {
        s1[r] = f1[i]; se1[r] = E1[i]; se1s[r] = E1s[i]; inv1[r] = i;
      } else {
        inv[r] = i; f2s[r] = f2[i]; eF2srt[r] = eF2[i]; eF2ssrt[r] = eF2s[i];
      }
    }
  }
}

// ============ K3: D-factors + kpos (LDS bsearch) + TU/TV chunk totals ============
__global__ __launch_bounds__(1024) void k_DT(
    const float* __restrict__ se1, const float* __restrict__ se1s,
    const float* __restrict__ s1g,
    const float* __restrict__ f2s, const float* __restrict__ eF2srt,
    const float* __restrict__ eF2ssrt, const int* __restrict__ inv,
    const float* __restrict__ seq,
    float* __restrict__ Bs, float* __restrict__ Es,
    int* __restrict__ kpos, float* __restrict__ TU, float* __restrict__ TV)
{
  __shared__ float s1l[NN];
  __shared__ float f2sl[NN];
  __shared__ float csA[256], csB[256];
  __shared__ float csEA[257], csEB[257];
  __shared__ float wsA[4], wsB[4];
  __shared__ float bsl[32], esl[32];
  __shared__ float redU[16][64], redV[16][64];
  const int t = threadIdx.x;
  const int b = blockIdx.x;
  const int wv = t >> 6, lane = t & 63;
  const float4 a0 = ((const float4*)se1 )[t*2];
  const float4 a1v = ((const float4*)se1 )[t*2+1];
  const float4 b0 = ((const float4*)se1s)[t*2];
  const float4 b1v = ((const float4*)se1s)[t*2+1];
  ((float4*)s1l)[t*2]   = ((const float4*)s1g)[t*2];
  ((float4*)s1l)[t*2+1] = ((const float4*)s1g)[t*2+1];
  ((float4*)f2sl)[t*2]   = ((const float4*)f2s)[t*2];
  ((float4*)f2sl)[t*2+1] = ((const float4*)f2s)[t*2+1];
  float sa = ((a0.x+a0.y)+(a0.z+a0.w)) + ((a1v.x+a1v.y)+(a1v.z+a1v.w));
  float sb = ((b0.x+b0.y)+(b0.z+b0.w)) + ((b1v.x+b1v.y)+(b1v.z+b1v.w));
  sa += __shfl_xor(sa, 1, 64); sb += __shfl_xor(sb, 1, 64);
  sa += __shfl_xor(sa, 2, 64); sb += __shfl_xor(sb, 2, 64);
  if ((t & 3) == 0) { csA[t>>2] = sa; csB[t>>2] = sb; }
  __syncthreads();
  if (t < 256) {
    float a = csA[t], bv = csB[t];
#pragma unroll
    for (int d = 1; d < 64; d <<= 1) {
      const float ua = __shfl_up(a, d, 64);
      const float ub = __shfl_up(bv, d, 64);
      if (lane >= d) { a += ua; bv += ub; }
    }
    csA[t] = a; csB[t] = bv;
    if (lane == 63) { wsA[wv] = a; wsB[wv] = bv; }
  }
  __syncthreads();
  if (t < 256) {
    float baseA = 0.f, baseB = 0.f;
    for (int q = 0; q < wv; ++q) { baseA += wsA[q]; baseB += wsB[q]; }
    csEA[t+1] = csA[t] + baseA;
    csEB[t+1] = csB[t] + baseB;
    if (t == 0) { csEA[0] = 0.f; csEB[0] = 0.f; }
  }
  __syncthreads();
  const int half = lane >> 5, m = lane & 31;
  {
    const int kk = b*32 + 2*wv + half;
    const float tgt = -f2sl[kk];
    int pos = 0;
#pragma unroll
    for (int s = NN; s; s >>= 1) {
      const int c = pos + s;
      if (c <= NN && s1l[c-1] < tgt) pos = c;
    }
    const int base = pos & ~31, cn = pos & 31;
    float ta = 0.f, tb = 0.f;
    if (m < cn) { ta = se1[base+m]; tb = se1s[base+m]; }
#pragma unroll
    for (int d = 1; d < 32; d <<= 1) {
      ta += __shfl_xor(ta, d, 64);
      tb += __shfl_xor(tb, d, 64);
    }
    if (m == 0) {
      const float PreA = csEA[pos>>5] + ta;
      const float PreB = csEB[pos>>5] + tb;
      const float T1 = csEA[256];
      const float e2 = eF2srt[kk], e2s = eF2ssrt[kk];
      const float D = fmaf(T1 - PreA, e2, PreB * e2s);
      const float bsv = e2 / D, esv = e2s / D;
      Bs[kk] = bsv; Es[kk] = esv;
      bsl[2*wv + half] = bsv; esl[2*wv + half] = esv;
    }
  }
  if (t < 32) {
    const int r = b*32 + t;
    const float tgt = -s1l[r];
    int pos = 0;
#pragma unroll
    for (int s = NN; s; s >>= 1) {
      const int c = pos + s;
      if (c <= NN && f2sl[c-1] < tgt) pos = c;
    }
    kpos[r] = pos;
  }
  __syncthreads();
  {
    const int kk0 = b*32 + 2*wv, kk1 = kk0 + 1;
    const float s0v = seq[(size_t)inv[kk0]*OO + lane];
    const float s1v = seq[(size_t)inv[kk1]*OO + lane];
    redU[wv][lane] = bsl[2*wv]*s0v + bsl[2*wv+1]*s1v;
    redV[wv][lane] = esl[2*wv]*s0v + esl[2*wv+1]*s1v;
  }
  __syncthreads();
  if (wv == 0) {
    float r = 0.f;
#pragma unroll
    for (int q = 0; q < 16; ++q) r += redU[q][lane];
    TU[b*64 + lane] = r;
  } else if (wv == 1) {
    float r = 0.f;
#pragma unroll
    for (int q = 0; q < 16; ++q) r += redV[q][lane];
    TV[b*64 + lane] = r;
  }
}

// ============ K4: merged prefix + output (no PU/PV tables), 1024 threads ============
__global__ __launch_bounds__(1024) void k_merge(
    const int* __restrict__ kpos, const int* __restrict__ inv,
    const int* __restrict__ inv1,
    const float* __restrict__ se1, const float* __restrict__ se1s,
    const float* __restrict__ Bs, const float* __restrict__ Es,
    const float* __restrict__ seq,
    const float* __restrict__ TU, const float* __restrict__ TV,
    float* __restrict__ out)
{
  __shared__ int kposl[NN];
  __shared__ float pu[33][64], pv[33][64];
  __shared__ float rA[16][64], rB[16][64], rC[16][64];
  __shared__ int bnd[2];
  const int t = threadIdx.x, lane = t & 63, wv = t >> 6, b = blockIdx.x;
  for (int q = t; q < NN/4; q += 1024)
    ((int4*)kposl)[q] = ((const int4*)kpos)[q];
  float pbu = 0.f, pbv = 0.f, ptu = 0.f;
  for (int c = wv; c < 256; c += 16) {
    const float tu = TU[c*64 + lane], tv = TV[c*64 + lane];
    ptu += tu;
    if (c < b) { pbu += tu; pbv += tv; }
  }
  rA[wv][lane] = pbu; rB[wv][lane] = pbv; rC[wv][lane] = ptu;
  {
    const int kk0 = b*32 + 2*wv, kk1 = kk0 + 1;
    const float sv0 = seq[(size_t)inv[kk0]*OO + lane];
    const float sv1 = seq[(size_t)inv[kk1]*OO + lane];
    pu[2*wv+1][lane] = Bs[kk0]*sv0; pv[2*wv+1][lane] = Es[kk0]*sv0;
    pu[2*wv+2][lane] = Bs[kk1]*sv1; pv[2*wv+2][lane] = Es[kk1]*sv1;
  }
  if (wv == 0) { pu[0][lane] = 0.f; pv[0][lane] = 0.f; }
  __syncthreads();
  if (t == 0) {
    const int hi = 32*b + 32 + (b == 255 ? 1 : 0);
    int pos = 0;
    for (int s = NN; s; s >>= 1) { const int c = pos+s; if (c <= NN && kposl[c-1] >= hi) pos = c; }
    bnd[0] = pos;
    pos = 0;
    const int lo = 32*b;
    for (int s = NN; s; s >>= 1) { const int c = pos+s; if (c <= NN && kposl[c-1] >= lo) pos = c; }
    bnd[1] = pos;
  }
  float base_u = 0.f, base_v = 0.f, utot = 0.f;
#pragma unroll
  for (int q = 0; q < 16; ++q) {
    base_u += rA[q][lane]; base_v += rB[q][lane]; utot += rC[q][lane];
  }
  for (int d = 1; d < 32; d <<= 1) {
    const int rowA = wv + 1;
    const int rowB = wv + 17;
    const int srcA = rowA - d, srcB = rowB - d;
    const float aA = (srcA >= 0) ? pu[srcA][lane] : 0.f;
    const float vA = (srcA >= 0) ? pv[srcA][lane] : 0.f;
    const float aB = (srcB >= 0) ? pu[srcB][lane] : 0.f;
    const float vB = (srcB >= 0) ? pv[srcB][lane] : 0.f;
    __syncthreads();
    pu[rowA][lane] += aA; pv[rowA][lane] += vA;
    pu[rowB][lane] += aB; pv[rowB][lane] += vB;
    __syncthreads();
  }
  const int r0 = bnd[0], r1 = bnd[1];
  for (int r = r0 + wv; r < r1; r += 16) {
    const int kl = kposl[r] - 32*b;
    const float ret = se1[r]*(utot - (base_u + pu[kl][lane]))
                    + se1s[r]*(base_v + pv[kl][lane]);
    out[(size_t)inv1[r]*OO + lane] = (ret > 0.f) ? ret : expm1f(ret);
  }
}

extern "C" void kernel_launch(void* const* d_in, const int* in_sizes, int n_in,
                              void* d_out, int out_size, void* d_ws, size_t ws_size,
                              hipStream_t stream)
{
  (void)in_sizes; (void)n_in; (void)out_size; (void)ws_size;
  const float* x   = (const float*)d_in[0];
  const float* W1  = (const float*)d_in[1];
  const float* b1  = (const float*)d_in[2];
  const float* a1  = (const float*)d_in[3];
  const float* ba1 = (const float*)d_in[4];
  const float* a2  = (const float*)d_in[5];
  const float* ba2 = (const float*)d_in[6];
  float* out = (float*)d_out;

  float* w = (float*)d_ws;
  size_t off = 0;
  auto alloc = [&](size_t n) { float* p = w + off; off += (n + 63) & ~(size_t)63; return p; };
  float* seq  = alloc((size_t)NN*OO);
  float* f1   = alloc(NN);
  float* f2   = alloc(NN);
  float* E1   = alloc(NN);
  float* E1s  = alloc(NN);
  float* eF2  = alloc(NN);
  float* eF2s = alloc(NN);
  unsigned long long* keys = (unsigned long long*)alloc((size_t)4*NN);
  int*   inv1 = (int*)alloc(NN);
  int*   inv  = (int*)alloc(NN);
  float* s1   = alloc(NN);
  float* se1  = alloc(NN);
  float* se1s = alloc(NN);
  float* f2s  = alloc(NN);
  float* eF2srt  = alloc(NN);
  float* eF2ssrt = alloc(NN);
  float* Bs   = alloc(NN);
  float* Es   = alloc(NN);
  int*   kpos = (int*)alloc(NN);
  float* TU   = alloc(256*64);
  float* TV   = alloc(256*64);

  k_gemm<<<512, 256, 0, stream>>>(x, W1, b1, a1, ba1, a2, ba2,
                                  seq, f1, f2, E1, E1s, eF2, eF2s, keys);
  k_rank<<<256, 512, 0, stream>>>(keys, f1, E1, E1s, f2, eF2, eF2s,
                                  s1, se1, se1s, inv1, f2s, eF2srt, eF2ssrt, inv);
  k_DT<<<256, 1024, 0, stream>>>(se1, se1s, s1, f2s, eF2srt, eF2ssrt,
                                 inv, seq, Bs, Es, kpos, TU, TV);
  k_merge<<<256, 1024, 0, stream>>>(kpos, inv, inv1, se1, se1s, Bs, Es,
                                    seq, TU, TV, out);
}